// Round 3
// baseline (13831.731 us; speedup 1.0000x reference)
//
#include <hip/hip_runtime.h>
#include <math.h>

// Problem constants (4, 19, 512, 512) fp32
#define BB 4
#define CC 19
#define HH 512
#define WW 512
#define NSLICE (BB * CC)        // 76
#define SLICE  (HH * WW)        // 262144
#define W4     (WW / 4)         // 128 float4 per row
#define EPS    1e-12f
#define NEGINF (-INFINITY)

// time-tiling params
#define TSTEPS 16
#define RROWS  64
#define AROWS  (RROWS + 2 * TSTEPS)   // 96 rows held in registers per thread
#define NPASS  (256 / TSTEPS)         // 16 passes
#define RBLK   (HH / RROWS)           // 8 row-blocks per slice

// ---------------------------------------------------------------------------
// init: cur0 = -x, border (i==0, i==511, j==0, j==511) = 1.0
__global__ void init_kernel(const float* __restrict__ x, float* __restrict__ cur) {
    int t = blockIdx.x * blockDim.x + threadIdx.x;   // over NSLICE*SLICE/4
    const float4* x4 = (const float4*)x;
    float4* c4 = (float4*)cur;
    float4 v = x4[t];
    int pix = t << 2;
    int s = pix & (SLICE - 1);
    int i = s >> 9;
    int j0 = s & 511;
    float4 o;
    o.x = -v.x; o.y = -v.y; o.z = -v.z; o.w = -v.w;
    if (i == 0 || i == HH - 1) {
        o.x = 1.0f; o.y = 1.0f; o.z = 1.0f; o.w = 1.0f;
    } else {
        if (j0 == 0)        o.x = 1.0f;
        if (j0 == WW - 4)   o.w = 1.0f;
    }
    c4[t] = o;
}

// ---------------------------------------------------------------------------
// one pass = TSTEPS fused maxpool*x steps.
// Block: 512 threads (8 waves) spanning the full 512-col width; thread = 1 column.
// Each thread holds AROWS rows of cur and x in registers. Horizontal 3-max via
// wave shuffles; cross-wave boundary columns via a double-buffered LDS snapshot.
// Vertical 3-max via rolling carry over the thread's own register column.
//
// __launch_bounds__(512, 1): under EITHER interpretation of the 2nd arg
// (1 block/CU or 1 wave/EU) the VGPR budget is >= 256, which is what the
// ~230-reg live set (cur[96]+xr[96]+temps) needs. (512,2) was interpreted as
// 2 blocks/CU -> 128-VGPR budget -> full scratch spill (R2: 780MB FETCH/pass).
__global__ __launch_bounds__(512, 1)
void pass_kernel(const float* __restrict__ in, const float* __restrict__ xg,
                 float* __restrict__ out) {
    const int tid  = threadIdx.x;        // column 0..511
    const int lane = tid & 63;
    const int wv   = tid >> 6;           // wave 0..7
    const int bc   = blockIdx.x / RBLK;  // slice 0..75
    const int brow = blockIdx.x % RBLK;  // row-block 0..7
    const int gstart = brow * RROWS - TSTEPS;

    // L63[p][w][a] = left-neighbor value for wave w (written by lane63 of wave w-1)
    // R0 [p][w][a] = value written by lane0 of wave w (read by lane63 of wave w-1)
    __shared__ float L63[2][9][AROWS];
    __shared__ float R0[2][9][AROWS];

    if (tid < AROWS) {
        L63[0][0][tid] = NEGINF; L63[1][0][tid] = NEGINF;
        R0[0][8][tid]  = NEGINF; R0[1][8][tid]  = NEGINF;
    }

    // load register tiles (coalesced: thread j reads column j)
    float cur[AROWS], xr[AROWS];
    const size_t sbase = (size_t)bc * SLICE;
#pragma unroll
    for (int a = 0; a < AROWS; ++a) {
        int grow = gstart + a;
        if (grow >= 0 && grow < HH) {          // uniform branch
            cur[a] = in[sbase + (size_t)grow * WW + tid];
            xr[a]  = xg[sbase + (size_t)grow * WW + tid];
        } else {
            cur[a] = NEGINF;
            xr[a]  = 1.0f;
        }
    }

    const float* rbase[2];
    rbase[0] = (lane == 63) ? &R0[0][wv + 1][0] : &L63[0][wv][0];
    rbase[1] = (lane == 63) ? &R0[1][wv + 1][0] : &L63[1][wv][0];
    float* wbase[2];
    wbase[0] = (lane == 63) ? &L63[0][wv + 1][0] : &R0[0][wv][0];
    wbase[1] = (lane == 63) ? &L63[1][wv + 1][0] : &R0[1][wv][0];

#pragma unroll
    for (int t = 1; t <= TSTEPS; ++t) {
        const int p = t & 1;
        // snapshot boundary columns (pre-step values) for rows read this step
        if (lane == 0 || lane == 63) {
            float* wp = wbase[p];
#pragma unroll
            for (int a = t - 1; a <= AROWS - t; ++a) wp[a] = cur[a];
        }
        __syncthreads();
        const float* rp = rbase[p];

        // hmax of a row: shuffle left/right within wave, LDS for wave-boundary lanes
        auto hmax = [&](float v, int a) -> float {
            float l = __shfl_up(v, 1);
            float r = __shfl_down(v, 1);
            float b = rp[a];
            l = (lane == 0)  ? b : l;
            r = (lane == 63) ? b : r;
            return fmaxf(fmaxf(l, v), r);
        };

        float hm1 = hmax(cur[t - 1], t - 1);
        float h0  = hmax(cur[t],     t);
#pragma unroll
        for (int r = t; r <= AROWS - 1 - t; ++r) {
            float hp1 = hmax(cur[r + 1], r + 1);
            cur[r] = fmaxf(fmaxf(hm1, h0), hp1) * xr[r];
            hm1 = h0; h0 = hp1;
        }
        // rows outside the image must stay -inf (maxpool pad semantics)
#pragma unroll
        for (int a = 0; a < AROWS; ++a) {
            if (a < TSTEPS || a >= AROWS - TSTEPS) {   // only candidates
                int grow = gstart + a;
                if (grow < 0 || grow >= HH) cur[a] = NEGINF;   // uniform
            }
        }
    }

    // store the R valid center rows
#pragma unroll
    for (int a = TSTEPS; a < TSTEPS + RROWS; ++a)
        out[sbase + (size_t)(gstart + a) * WW + tid] = cur[a];
}

// ---------------------------------------------------------------------------
// final: norm over channel dim (19), out = cur * x / max(||cur||_2, eps)
__global__ void norm_kernel(const float* __restrict__ cur,
                            const float* __restrict__ x,
                            float* __restrict__ out) {
    int t = blockIdx.x * blockDim.x + threadIdx.x;   // over BB * HH * W4
    int j4 = t & (W4 - 1);
    int i  = (t >> 7) & (HH - 1);
    int b  = t >> 16;
    size_t off = (size_t)b * CC * SLICE + (size_t)i * WW + (j4 << 2);

    float4 vals[CC];
    float sx = 0.f, sy = 0.f, sz = 0.f, sw = 0.f;
#pragma unroll
    for (int c = 0; c < CC; ++c) {
        float4 v = *(const float4*)(cur + off + (size_t)c * SLICE);
        vals[c] = v;
        sx += v.x * v.x; sy += v.y * v.y; sz += v.z * v.z; sw += v.w * v.w;
    }
    float4 r;
    r.x = 1.0f / fmaxf(sqrtf(sx), EPS);
    r.y = 1.0f / fmaxf(sqrtf(sy), EPS);
    r.z = 1.0f / fmaxf(sqrtf(sz), EPS);
    r.w = 1.0f / fmaxf(sqrtf(sw), EPS);
#pragma unroll
    for (int c = 0; c < CC; ++c) {
        float4 xv = *(const float4*)(x + off + (size_t)c * SLICE);
        float4 o;
        o.x = vals[c].x * xv.x * r.x;
        o.y = vals[c].y * xv.y * r.y;
        o.z = vals[c].z * xv.z * r.z;
        o.w = vals[c].w * xv.w * r.w;
        *(float4*)(out + off + (size_t)c * SLICE) = o;
    }
}

// ---------------------------------------------------------------------------
extern "C" void kernel_launch(void* const* d_in, const int* in_sizes, int n_in,
                              void* d_out, int out_size, void* d_ws, size_t ws_size,
                              hipStream_t stream) {
    const float* x = (const float*)d_in[0];
    float* out = (float*)d_out;
    float* ws  = (float*)d_ws;        // >= 79,691,776 B

    const int initBlocks = NSLICE * SLICE / 4 / 256; // 19456
    const int passBlocks = NSLICE * RBLK;            // 608
    const int normBlocks = BB * HH * W4 / 256;       // 1024

    init_kernel<<<initBlocks, 256, 0, stream>>>(x, ws);
    float* a = ws;
    float* b = out;
    for (int it = 0; it < NPASS; ++it) {
        pass_kernel<<<passBlocks, 512, 0, stream>>>(a, x, b);
        float* tmp = a; a = b; b = tmp;
    }
    // NPASS even -> result back in ws
    norm_kernel<<<normBlocks, 256, 0, stream>>>(ws, x, out);
}

// Round 4
// 2552.393 us; speedup vs baseline: 5.4191x; 5.4191x over previous
//
#include <hip/hip_runtime.h>
#include <math.h>

// Problem constants (4, 19, 512, 512) fp32
#define BB 4
#define CC 19
#define HH 512
#define WW 512
#define NSLICE (BB * CC)        // 76
#define SLICE  (HH * WW)        // 262144
#define W4     (WW / 4)         // 128 float4 per row
#define EPS    1e-12f
#define NEGINF (-INFINITY)

// time-tiling params
#define TSTEPS 16
#define RROWS  64
#define AROWS  96               // RROWS + 2*TSTEPS
#define NPASS  16               // 256 / TSTEPS
#define RBLK   8                // HH / RROWS

// thread geometry: 64 threads across (8 cols each) x 8 thread-rows (12 rows each)
#define TX   64
#define TY   8
#define COLS 8
#define ROWS 12

struct F8 { float4 a, b; };

// ---------------------------------------------------------------------------
__global__ void init_kernel(const float* __restrict__ x, float* __restrict__ cur) {
    int t = blockIdx.x * blockDim.x + threadIdx.x;
    const float4* x4 = (const float4*)x;
    float4* c4 = (float4*)cur;
    float4 v = x4[t];
    int pix = t << 2;
    int s = pix & (SLICE - 1);
    int i = s >> 9;
    int j0 = s & 511;
    float4 o;
    o.x = -v.x; o.y = -v.y; o.z = -v.z; o.w = -v.w;
    if (i == 0 || i == HH - 1) {
        o.x = 1.0f; o.y = 1.0f; o.z = 1.0f; o.w = 1.0f;
    } else {
        if (j0 == 0)        o.x = 1.0f;
        if (j0 == WW - 4)   o.w = 1.0f;
    }
    c4[t] = o;
}

// ---------------------------------------------------------------------------
// one pass = TSTEPS fused (maxpool3x3 * x) steps on a 512x96 tile.
// thread = 8 cols x 12 rows register patch; wave = one 12-row strip spanning
// the full 512-col width. Horizontal 3-max: 2 in-wave shuffles per row.
// Vertical 3-max: rolling carry in registers; cross-thread row halos via LDS
// (9-word lane stride -> conflict-free). All loop trips/indices compile-time
// constant so cur/x arrays stay in VGPRs (R2/R3 failure: t-dependent bounds
// -> dynamic indexing -> scratch spill, 780MB FETCH/pass).
__global__ __launch_bounds__(512, 1)
void pass_kernel(const float* __restrict__ in, const float* __restrict__ xg,
                 float* __restrict__ out) {
    const int tid  = threadIdx.x;
    const int tx   = tid & 63;          // lane = column group
    const int ty   = tid >> 6;          // wave = thread-row
    const int bc   = blockIdx.x / RBLK;
    const int brow = blockIdx.x % RBLK;
    const int gstart = brow * RROWS - TSTEPS;       // tile row a=0 -> global row
    const int row0   = gstart + ty * ROWS;          // this thread's r=0 global row
    const int col0   = tx * COLS;
    const size_t sbase = (size_t)bc * SLICE;

    // LDS halo exchange: 8 floats per thread, 9-word lane stride (gcd(9,32)=1
    // -> 2-way bank aliasing only, which is free on wave64)
    __shared__ float Tb[TY][TX * 9];
    __shared__ float Bb[TY][TX * 9];

    const float4 neg4 = make_float4(NEGINF, NEGINF, NEGINF, NEGINF);
    const float4 one4 = make_float4(1.f, 1.f, 1.f, 1.f);

    float4 cl[ROWS], cr[ROWS], xl[ROWS], xr_[ROWS];

#pragma unroll
    for (int r = 0; r < ROWS; ++r) {
        int grow = row0 + r;
        if (grow >= 0 && grow < HH) {               // wave-uniform branch
            const float4* p = (const float4*)(in + sbase + (size_t)grow * WW + col0);
            cl[r] = p[0]; cr[r] = p[1];
            const float4* q = (const float4*)(xg + sbase + (size_t)grow * WW + col0);
            xl[r] = q[0]; xr_[r] = q[1];
        } else {
            cl[r] = neg4; cr[r] = neg4; xl[r] = one4; xr_[r] = one4;
        }
    }

    // horizontal 3-max of one 8-px row (a=cols0-3, b=cols4-7)
    auto hrow = [&](float4 a, float4 b) -> F8 {
        float lpx = __shfl_up(b.w, 1);
        float rpx = __shfl_down(a.x, 1);
        if (tx == 0)  lpx = NEGINF;    // image left pad
        if (tx == 63) rpx = NEGINF;    // image right pad
        F8 h;
        h.a.x = fmaxf(fmaxf(lpx, a.x), a.y);
        h.a.y = fmaxf(fmaxf(a.x, a.y), a.z);
        h.a.z = fmaxf(fmaxf(a.y, a.z), a.w);
        h.a.w = fmaxf(fmaxf(a.z, a.w), b.x);
        h.b.x = fmaxf(fmaxf(a.w, b.x), b.y);
        h.b.y = fmaxf(fmaxf(b.x, b.y), b.z);
        h.b.z = fmaxf(fmaxf(b.y, b.z), b.w);
        h.b.w = fmaxf(fmaxf(b.z, b.w), rpx);
        return h;
    };

    float* tp = &Tb[ty][tx * 9];
    float* bp = &Bb[ty][tx * 9];

    for (int t = 0; t < TSTEPS; ++t) {
        // snapshot pre-step top/bottom rows for vertical neighbors
        tp[0] = cl[0].x;  tp[1] = cl[0].y;  tp[2] = cl[0].z;  tp[3] = cl[0].w;
        tp[4] = cr[0].x;  tp[5] = cr[0].y;  tp[6] = cr[0].z;  tp[7] = cr[0].w;
        bp[0] = cl[11].x; bp[1] = cl[11].y; bp[2] = cl[11].z; bp[3] = cl[11].w;
        bp[4] = cr[11].x; bp[5] = cr[11].y; bp[6] = cr[11].z; bp[7] = cr[11].w;
        __syncthreads();

        float4 upA, upB, dnA, dnB;
        if (ty > 0) {                    // wave-uniform
            const float* q = &Bb[ty - 1][tx * 9];
            upA = make_float4(q[0], q[1], q[2], q[3]);
            upB = make_float4(q[4], q[5], q[6], q[7]);
        } else { upA = neg4; upB = neg4; }
        if (ty < TY - 1) {
            const float* q = &Tb[ty + 1][tx * 9];
            dnA = make_float4(q[0], q[1], q[2], q[3]);
            dnB = make_float4(q[4], q[5], q[6], q[7]);
        } else { dnA = neg4; dnB = neg4; }

        F8 hA = hrow(upA, upB);          // row r-1 (neighbor)
        F8 hB = hrow(cl[0], cr[0]);      // row r
#pragma unroll
        for (int r = 0; r < ROWS; ++r) {
            F8 hC;
            if (r + 1 < ROWS) hC = hrow(cl[r + 1], cr[r + 1]);
            else              hC = hrow(dnA, dnB);
            float4 vl, vr;
            vl.x = fmaxf(fmaxf(hA.a.x, hB.a.x), hC.a.x);
            vl.y = fmaxf(fmaxf(hA.a.y, hB.a.y), hC.a.y);
            vl.z = fmaxf(fmaxf(hA.a.z, hB.a.z), hC.a.z);
            vl.w = fmaxf(fmaxf(hA.a.w, hB.a.w), hC.a.w);
            vr.x = fmaxf(fmaxf(hA.b.x, hB.b.x), hC.b.x);
            vr.y = fmaxf(fmaxf(hA.b.y, hB.b.y), hC.b.y);
            vr.z = fmaxf(fmaxf(hA.b.z, hB.b.z), hC.b.z);
            vr.w = fmaxf(fmaxf(hA.b.w, hB.b.w), hC.b.w);
            cl[r].x = vl.x * xl[r].x;  cl[r].y = vl.y * xl[r].y;
            cl[r].z = vl.z * xl[r].z;  cl[r].w = vl.w * xl[r].w;
            cr[r].x = vr.x * xr_[r].x; cr[r].y = vr.y * xr_[r].y;
            cr[r].z = vr.z * xr_[r].z; cr[r].w = vr.w * xr_[r].w;
            hA = hB; hB = hC;
        }
        // rows outside the image must be -inf before the next step's reads
#pragma unroll
        for (int r = 0; r < ROWS; ++r) {
            int grow = row0 + r;
            if (grow < 0 || grow >= HH) { cl[r] = neg4; cr[r] = neg4; }  // uniform
        }
        __syncthreads();                 // protect LDS snapshot until reads done
    }

    // store valid center rows: tile rows a in [TSTEPS, TSTEPS+RROWS)
#pragma unroll
    for (int r = 0; r < ROWS; ++r) {
        int a = ty * ROWS + r;           // wave-uniform condition
        if (a >= TSTEPS && a < TSTEPS + RROWS) {
            int grow = row0 + r;
            float4* p = (float4*)(out + sbase + (size_t)grow * WW + col0);
            p[0] = cl[r]; p[1] = cr[r];
        }
    }
}

// ---------------------------------------------------------------------------
// final: norm over channel dim (19), out = cur * x / max(||cur||_2, eps)
__global__ void norm_kernel(const float* __restrict__ cur,
                            const float* __restrict__ x,
                            float* __restrict__ out) {
    int t = blockIdx.x * blockDim.x + threadIdx.x;
    int j4 = t & (W4 - 1);
    int i  = (t >> 7) & (HH - 1);
    int b  = t >> 16;
    size_t off = (size_t)b * CC * SLICE + (size_t)i * WW + (j4 << 2);

    float4 vals[CC];
    float sx = 0.f, sy = 0.f, sz = 0.f, sw = 0.f;
#pragma unroll
    for (int c = 0; c < CC; ++c) {
        float4 v = *(const float4*)(cur + off + (size_t)c * SLICE);
        vals[c] = v;
        sx += v.x * v.x; sy += v.y * v.y; sz += v.z * v.z; sw += v.w * v.w;
    }
    float4 r;
    r.x = 1.0f / fmaxf(sqrtf(sx), EPS);
    r.y = 1.0f / fmaxf(sqrtf(sy), EPS);
    r.z = 1.0f / fmaxf(sqrtf(sz), EPS);
    r.w = 1.0f / fmaxf(sqrtf(sw), EPS);
#pragma unroll
    for (int c = 0; c < CC; ++c) {
        float4 xv = *(const float4*)(x + off + (size_t)c * SLICE);
        float4 o;
        o.x = vals[c].x * xv.x * r.x;
        o.y = vals[c].y * xv.y * r.y;
        o.z = vals[c].z * xv.z * r.z;
        o.w = vals[c].w * xv.w * r.w;
        *(float4*)(out + off + (size_t)c * SLICE) = o;
    }
}

// ---------------------------------------------------------------------------
extern "C" void kernel_launch(void* const* d_in, const int* in_sizes, int n_in,
                              void* d_out, int out_size, void* d_ws, size_t ws_size,
                              hipStream_t stream) {
    const float* x = (const float*)d_in[0];
    float* out = (float*)d_out;
    float* ws  = (float*)d_ws;        // >= 79,691,776 B

    const int initBlocks = NSLICE * SLICE / 4 / 256; // 19456
    const int passBlocks = NSLICE * RBLK;            // 608
    const int normBlocks = BB * HH * W4 / 256;       // 1024

    init_kernel<<<initBlocks, 256, 0, stream>>>(x, ws);
    float* a = ws;
    float* b = out;
    for (int it = 0; it < NPASS; ++it) {
        pass_kernel<<<passBlocks, 512, 0, stream>>>(a, x, b);
        float* tmp = a; a = b; b = tmp;
    }
    // NPASS even -> result back in ws
    norm_kernel<<<normBlocks, 256, 0, stream>>>(ws, x, out);
}